// Round 7
// baseline (269.993 us; speedup 1.0000x reference)
//
#include <hip/hip_runtime.h>
#include <hip/hip_bf16.h>
#include <stdint.h>

#define NPTS 131072
#define DIM  512
#define KC   512
#define BM   64
#define NKT  16          // DIM / 32

typedef float f32x16 __attribute__((ext_vector_type(16)));
typedef float f32x4  __attribute__((ext_vector_type(4)));
typedef short bf16x8 __attribute__((ext_vector_type(8)));

__device__ __forceinline__ float sq4(f32x4 a) {
  return a.x*a.x + a.y*a.y + a.z*a.z + a.w*a.w;
}

// packed RNE fp32->bf16 (v_cvt_pk_bf16_f32)
__device__ __forceinline__ bf16x8 pack8c(f32x4 a, f32x4 b) {
  bf16x8 r;
  float v[8] = {a.x, a.y, a.z, a.w, b.x, b.y, b.z, b.w};
  #pragma unroll
  for (int i = 0; i < 4; ++i) {
    __hip_bfloat162 t = __float22bfloat162_rn(make_float2(v[2*i], v[2*i+1]));
    union { __hip_bfloat162 h; short s[2]; } u; u.h = t;
    r[2*i]   = u.s[0];
    r[2*i+1] = u.s[1];
  }
  return r;
}

// scalar RNE (pre-kernel only)
__device__ __forceinline__ short f2bf(float f) {
  union { float f; unsigned u; } v; v.f = f;
  unsigned r = v.u + 0x7FFFu + ((v.u >> 16) & 1u);
  return (short)(r >> 16);
}
__device__ __forceinline__ bf16x8 pack8(f32x4 a, f32x4 b) {
  bf16x8 p;
  p[0] = f2bf(a.x); p[1] = f2bf(a.y); p[2] = f2bf(a.z); p[3] = f2bf(a.w);
  p[4] = f2bf(b.x); p[5] = f2bf(b.y); p[6] = f2bf(b.z); p[7] = f2bf(b.w);
  return p;
}

// ---------------------------------------------------------------------------
// Pre-kernel (same layout as R5/R6): clusters fp32 [512][512] -> bf16 packed
// in MFMA-fragment order: short offset = kt*16384 + s*8192 + wn*2048 +
// nt*512 + (h*32+r)*8, holding B[n=wn*128+nt*32+r][k=kt*32+s*16+h*8+j].
// Main kernel reads fragments straight to registers: contiguous 1 KB per
// wave-instruction, L2-resident (512 KB). Also c2[n] = ||c_n||^2 (fp32).
// ---------------------------------------------------------------------------
__global__ void dec_pack(const float* __restrict__ C, short* __restrict__ Bp,
                         float* __restrict__ c2) {
  const int n    = blockIdx.x;
  const int lane = threadIdx.x;
  const float* src = C + (size_t)n * DIM + lane * 8;
  f32x4 v0 = *(const f32x4*)src;
  f32x4 v1 = *(const f32x4*)(src + 4);
  float s = sq4(v0) + sq4(v1);
  #pragma unroll
  for (int m = 1; m < 64; m <<= 1) s += __shfl_xor(s, m, 64);
  if (lane == 0) c2[n] = s;
  const int kt = lane >> 2;
  const int st = (lane >> 1) & 1;
  const int hh = lane & 1;
  const int wn = n >> 7, nt = (n >> 5) & 3, r = n & 31;
  const size_t slot =
      (((size_t)(kt * 2 + st) * 4 + wn) * 4 + nt) * 64 + hh * 32 + r;
  *(bf16x8*)(Bp + slot * 8) = pack8(v0, v1);
}

// ---------------------------------------------------------------------------
// Main fused kernel — NO LDS, NO barriers, NO cross-lane ops in the K loop.
// 512 threads = 8 waves (wm = wave>>2, wn = wave&3); block tile 64 x 512.
// Wave tile 32x128 via 8 x mfma_f32_32x32x16_bf16 per kt (BK=32).
//
// A operand loaded DIRECTLY from X in fragment layout: lane l31 (k-half h)
// reads X[row0+wm*32+l31][kt*32+s*16+h*8 .. +7] as 2 x dwordx4. Per load
// instruction: 32 rows x one 64B sector, 100% of each sector consumed by the
// two h-lanes -> zero overfetch; all offsets fold to base + imm (<4 KB).
// fp32->bf16 cvt_pk + exact-fp32 x2 accumulation happen in-register.
// B operand: pre-packed fragment-order loads (1 KB contiguous / instr,
// L2-resident). 1-iteration ping-pong prefetch, A issued before B so vmcnt
// retirement order matches consume order (cvt(A) first, MFMA(B) after).
// Epilogue: x2 via one shfl_xor; q = rcp(1+d2); butterfly row-sums; one
// barrier to combine the 4 wn partials; normalize; coalesced stores.
// ---------------------------------------------------------------------------
__global__ __launch_bounds__(512)
void dec_main(const float* __restrict__ X, const short* __restrict__ Bp,
              const float* __restrict__ c2g, float* __restrict__ out) {
  __shared__ float part[4][BM];
  __shared__ float rowinv[BM];

  const int tid  = threadIdx.x;
  const int lane = tid & 63;
  const int wave = tid >> 6;
  const int wm   = wave >> 2;   // 0..1 : row half
  const int wn   = wave & 3;    // 0..3 : column quarter
  const int l31  = lane & 31;
  const int h    = lane >> 5;
  const int row0 = blockIdx.x * BM;

  // A: lane reads row (row0+wm*32+l31), floats kt*32 + s*16 + h*8 (+0,+4)
  const float* ap = X + (size_t)(row0 + wm * 32 + l31) * DIM + h * 8;
  // B: + kt*16384 + s*8192 + nt*512 (shorts)
  const short* bp = Bp + wn * 2048 + lane * 8;

  f32x16 acc[4];
  #pragma unroll
  for (int nt = 0; nt < 4; ++nt) acc[nt] = (f32x16)0.f;
  float x2 = 0.f;

  f32x4 aA[2][2], aB[2][2];
  bf16x8 bA[2][4], bB[2][4];

#define LOADA(dst, kt)                                                   \
  {                                                                      \
    _Pragma("unroll")                                                    \
    for (int s = 0; s < 2; ++s) {                                        \
      dst[s][0] = *(const f32x4*)(ap + (kt) * 32 + s * 16);              \
      dst[s][1] = *(const f32x4*)(ap + (kt) * 32 + s * 16 + 4);          \
    }                                                                    \
  }
#define LOADB(dst, kt)                                                   \
  {                                                                      \
    _Pragma("unroll")                                                    \
    for (int s = 0; s < 2; ++s)                                          \
      _Pragma("unroll")                                                  \
      for (int nt = 0; nt < 4; ++nt)                                     \
        dst[s][nt] = *(const bf16x8*)(bp + (kt) * 16384 + s * 8192 +     \
                                      nt * 512);                         \
  }
#define CONSUME(a, b)                                                    \
  {                                                                      \
    bf16x8 af[2];                                                        \
    _Pragma("unroll")                                                    \
    for (int s = 0; s < 2; ++s) {                                        \
      x2 += sq4(a[s][0]) + sq4(a[s][1]);                                 \
      af[s] = pack8c(a[s][0], a[s][1]);                                  \
    }                                                                    \
    _Pragma("unroll")                                                    \
    for (int s = 0; s < 2; ++s)                                          \
      _Pragma("unroll")                                                  \
      for (int nt = 0; nt < 4; ++nt)                                     \
        acc[nt] = __builtin_amdgcn_mfma_f32_32x32x16_bf16(               \
            af[s], b[s][nt], acc[nt], 0, 0, 0);                          \
  }

  // prologue: kt=0 into the A set
  LOADA(aA, 0);
  LOADB(bA, 0);

  #pragma unroll
  for (int kt = 0; kt < NKT; kt += 2) {
    // prefetch kt+1 into B set (A loads first: HBM, retire first)
    LOADA(aB, kt + 1);
    LOADB(bB, kt + 1);
    CONSUME(aA, bA);
    // prefetch kt+2 into A set (clamped on last iter; dead loads)
    const int k2 = (kt + 2 < NKT) ? (kt + 2) : (NKT - 2);
    LOADA(aA, k2);
    LOADB(bA, k2);
    CONSUME(aB, bB);
  }
#undef LOADA
#undef LOADB
#undef CONSUME

  // ---- x2: combine the two k-halves; lane l then holds x2(row l31) ----
  x2 += __shfl_xor(x2, 32, 64);

  float c2v[4];
  #pragma unroll
  for (int nt = 0; nt < 4; ++nt) c2v[nt] = c2g[wn * 128 + nt * 32 + l31];

  // ---- q = rcp(1+d2), per-row partial sums over this wave's 128 cols ----
  float srow[16];
  #pragma unroll
  for (int r = 0; r < 16; ++r) {
    const int mloc = (r & 3) + 8 * (r >> 2) + 4 * h;   // 0..31
    const float x2m = __shfl(x2, mloc, 64);
    float s = 0.f;
    #pragma unroll
    for (int nt = 0; nt < 4; ++nt) {
      float d2 = fmaxf(x2m + c2v[nt] - 2.f * acc[nt][r], 0.f);
      float q = __builtin_amdgcn_rcpf(1.f + d2);
      acc[nt][r] = q;
      s += q;
    }
    #pragma unroll
    for (int msk = 1; msk < 32; msk <<= 1) s += __shfl_xor(s, msk, 64);
    srow[r] = s;
  }

  if (l31 == 0) {
    #pragma unroll
    for (int r = 0; r < 16; ++r)
      part[wn][wm * 32 + (r & 3) + 8 * (r >> 2) + 4 * h] = srow[r];
  }
  __syncthreads();
  if (tid < BM)
    rowinv[tid] = __builtin_amdgcn_rcpf(part[0][tid] + part[1][tid] +
                                        part[2][tid] + part[3][tid]);
  __syncthreads();

  // ---- normalize + coalesced stores ----
  #pragma unroll
  for (int r = 0; r < 16; ++r) {
    const int row = wm * 32 + (r & 3) + 8 * (r >> 2) + 4 * h;
    const float iv = rowinv[row];
    float* o = out + (size_t)(row0 + row) * KC + wn * 128 + l31;
    #pragma unroll
    for (int nt = 0; nt < 4; ++nt)
      o[nt * 32] = acc[nt][r] * iv;
  }
}

extern "C" void kernel_launch(void* const* d_in, const int* in_sizes, int n_in,
                              void* d_out, int out_size, void* d_ws, size_t ws_size,
                              hipStream_t stream) {
  const float* X = (const float*)d_in[0];   // inputs  [131072, 512] fp32
  const float* C = (const float*)d_in[1];   // clusters [512, 512] fp32
  float* out = (float*)d_out;               // [131072, 512] fp32

  short* Bp = (short*)d_ws;                                   // 512 KB packed bf16 clusters
  float* c2 = (float*)((char*)d_ws + (size_t)KC * DIM * 2);   // 2 KB cluster norms

  dec_pack<<<KC, 64, 0, stream>>>(C, Bp, c2);
  dec_main<<<NPTS / BM, 512, 0, stream>>>(X, Bp, c2, out);
}